// Round 1
// baseline (1696.121 us; speedup 1.0000x reference)
//
#include <hip/hip_runtime.h>
#include <math.h>

// ---------------- helpers ----------------

__device__ __forceinline__ unsigned fenc(float f) {
    unsigned u = __float_as_uint(f);
    return (u & 0x80000000u) ? ~u : (u | 0x80000000u);
}
__device__ __forceinline__ float fdec(unsigned u) {
    unsigned v = (u & 0x80000000u) ? (u ^ 0x80000000u) : ~u;
    return __uint_as_float(v);
}
__device__ __forceinline__ float lrelu(float x) { return x > 0.f ? x : 0.2f * x; }

// ---------------- layer-1 GEMM: xw = x @ W1  [N,128]x[128,128], fused alpha dots ----------------
// block 256: cg = tid&31 -> 4 cols, ng = tid>>5 -> 4 nodes. 32 nodes/block.
__global__ __launch_bounds__(256) void k_gemm1(
    const float* __restrict__ x, const float* __restrict__ W,
    const float* __restrict__ att_s, const float* __restrict__ att_d,
    float* __restrict__ xw, float* __restrict__ asrc, float* __restrict__ adst, int N)
{
    __shared__ float ws[64 * 128];   // half of W (32KB)
    __shared__ float xs[128 * 32];   // x tile transposed [k][node] (16KB)
    const int tid = threadIdx.x;
    const int cg = tid & 31;
    const int ng = tid >> 5;
    const int nb = blockIdx.x * 32;

    #pragma unroll
    for (int i = 0; i < 16; i++) {
        int q = i * 256 + tid;        // q = nl*128 + k
        int nl = q >> 7, k = q & 127;
        int n = nb + nl;
        xs[k * 32 + nl] = (n < N) ? x[(size_t)n * 128 + k] : 0.f;
    }

    float acc[4][4];
    #pragma unroll
    for (int i = 0; i < 4; i++)
        #pragma unroll
        for (int j = 0; j < 4; j++) acc[i][j] = 0.f;

    for (int half = 0; half < 2; half++) {
        __syncthreads();
        #pragma unroll
        for (int i = 0; i < 32; i++) {
            int q = i * 256 + tid;
            ws[q] = W[half * 8192 + q];
        }
        __syncthreads();
        #pragma unroll 8
        for (int kk = 0; kk < 64; kk++) {
            int k = half * 64 + kk;
            float4 wv = ((const float4*)ws)[kk * 32 + cg];
            float4 xv = ((const float4*)xs)[k * 8 + ng];
            float xa[4] = {xv.x, xv.y, xv.z, xv.w};
            float wa[4] = {wv.x, wv.y, wv.z, wv.w};
            #pragma unroll
            for (int i = 0; i < 4; i++)
                #pragma unroll
                for (int j = 0; j < 4; j++)
                    acc[i][j] += xa[i] * wa[j];
        }
    }

    const int c0 = cg * 4;
    #pragma unroll
    for (int i = 0; i < 4; i++) {
        int n = nb + ng * 4 + i;
        float t1 = acc[i][0] * att_s[c0 + 0] + acc[i][1] * att_s[c0 + 1] +
                   acc[i][2] * att_s[c0 + 2] + acc[i][3] * att_s[c0 + 3];
        float t2 = acc[i][0] * att_d[c0 + 0] + acc[i][1] * att_d[c0 + 1] +
                   acc[i][2] * att_d[c0 + 2] + acc[i][3] * att_d[c0 + 3];
        t1 += __shfl_xor(t1, 1, 8); t1 += __shfl_xor(t1, 2, 8); t1 += __shfl_xor(t1, 4, 8);
        t2 += __shfl_xor(t2, 1, 8); t2 += __shfl_xor(t2, 2, 8); t2 += __shfl_xor(t2, 4, 8);
        if (n < N) {
            ((float4*)xw)[(size_t)n * 32 + cg] =
                make_float4(acc[i][0], acc[i][1], acc[i][2], acc[i][3]);
            if ((cg & 7) == 0) {
                asrc[n * 4 + (cg >> 3)] = t1;
                adst[n * 4 + (cg >> 3)] = t2;
            }
        }
    }
}

// ---------------- layer-2 GEMM: xw2 = h @ W2 [N,128]x[128,32], fused alpha dots ----------------
// block 256: cg = tid&7 -> 4 cols, ng = tid>>3 -> 2 nodes. 64 nodes/block.
__global__ __launch_bounds__(256) void k_gemm2(
    const float* __restrict__ h, const float* __restrict__ W,
    const float* __restrict__ att_s, const float* __restrict__ att_d,
    float* __restrict__ xw, float* __restrict__ asrc, float* __restrict__ adst, int N)
{
    __shared__ float ws[128 * 32];  // 16KB
    __shared__ float xs[128 * 64];  // 32KB, transposed [k][node]
    const int tid = threadIdx.x;
    const int cg = tid & 7;
    const int ng = tid >> 3;
    const int nb = blockIdx.x * 64;

    #pragma unroll
    for (int i = 0; i < 16; i++) { int q = i * 256 + tid; ws[q] = W[q]; }
    #pragma unroll
    for (int i = 0; i < 32; i++) {
        int q = i * 256 + tid;
        int nl = q >> 7, k = q & 127;
        int n = nb + nl;
        xs[k * 64 + nl] = (n < N) ? h[(size_t)n * 128 + k] : 0.f;
    }
    __syncthreads();

    float acc[2][4];
    #pragma unroll
    for (int i = 0; i < 2; i++)
        #pragma unroll
        for (int j = 0; j < 4; j++) acc[i][j] = 0.f;

    #pragma unroll 8
    for (int k = 0; k < 128; k++) {
        float4 wv = ((const float4*)ws)[k * 8 + cg];
        float2 xv = ((const float2*)xs)[k * 32 + ng];
        float wa[4] = {wv.x, wv.y, wv.z, wv.w};
        #pragma unroll
        for (int j = 0; j < 4; j++) {
            acc[0][j] += xv.x * wa[j];
            acc[1][j] += xv.y * wa[j];
        }
    }

    const int c0 = cg * 4;
    #pragma unroll
    for (int i = 0; i < 2; i++) {
        int n = nb + ng * 2 + i;
        float t1 = acc[i][0] * att_s[c0 + 0] + acc[i][1] * att_s[c0 + 1] +
                   acc[i][2] * att_s[c0 + 2] + acc[i][3] * att_s[c0 + 3];
        float t2 = acc[i][0] * att_d[c0 + 0] + acc[i][1] * att_d[c0 + 1] +
                   acc[i][2] * att_d[c0 + 2] + acc[i][3] * att_d[c0 + 3];
        t1 += __shfl_xor(t1, 1, 8); t1 += __shfl_xor(t1, 2, 8); t1 += __shfl_xor(t1, 4, 8);
        t2 += __shfl_xor(t2, 1, 8); t2 += __shfl_xor(t2, 2, 8); t2 += __shfl_xor(t2, 4, 8);
        if (n < N) {
            ((float4*)xw)[(size_t)n * 8 + cg] =
                make_float4(acc[i][0], acc[i][1], acc[i][2], acc[i][3]);
            if (cg == 0) { asrc[n] = t1; adst[n] = t2; }
        }
    }
}

// ---------------- edge max, layer 1 (4 heads) ----------------
__global__ __launch_bounds__(256) void k_edge_max1(
    const int* __restrict__ ei, const float4* __restrict__ as, const float4* __restrict__ ad,
    unsigned* __restrict__ m, int E, int ET)
{
    int t = blockIdx.x * 256 + threadIdx.x;
    if (t >= ET) return;
    int s, d;
    if (t < E) { s = ei[t]; d = ei[E + t]; } else { s = d = t - E; }
    float4 a = as[s], b = ad[d];
    atomicMax(&m[d * 4 + 0], fenc(lrelu(a.x + b.x)));
    atomicMax(&m[d * 4 + 1], fenc(lrelu(a.y + b.y)));
    atomicMax(&m[d * 4 + 2], fenc(lrelu(a.z + b.z)));
    atomicMax(&m[d * 4 + 3], fenc(lrelu(a.w + b.w)));
}

// ---------------- edge scatter, layer 1: wave per edge ----------------
__global__ __launch_bounds__(256) void k_scatter1(
    const int* __restrict__ ei, const float4* __restrict__ as, const float4* __restrict__ ad,
    const unsigned* __restrict__ m, const float* __restrict__ xw,
    float* __restrict__ den, float* __restrict__ acc, int E, int ET)
{
    int t = blockIdx.x * 4 + (threadIdx.x >> 6);
    int lane = threadIdx.x & 63;
    if (t >= ET) return;
    int s, d;
    if (t < E) { s = ei[t]; d = ei[E + t]; } else { s = d = t - E; }
    float4 a = as[s], b = ad[d];
    float eh0 = __expf(lrelu(a.x + b.x) - fdec(m[d * 4 + 0]));
    float eh1 = __expf(lrelu(a.y + b.y) - fdec(m[d * 4 + 1]));
    float eh2 = __expf(lrelu(a.z + b.z) - fdec(m[d * 4 + 2]));
    float eh3 = __expf(lrelu(a.w + b.w) - fdec(m[d * 4 + 3]));
    if (lane == 0) {
        atomicAdd(&den[d * 4 + 0], eh0);
        atomicAdd(&den[d * 4 + 1], eh1);
        atomicAdd(&den[d * 4 + 2], eh2);
        atomicAdd(&den[d * 4 + 3], eh3);
    }
    // lane handles channels lane (heads 0/1) and lane+64 (heads 2/3)
    float exLo = (lane < 32) ? eh0 : eh1;
    float exHi = (lane < 32) ? eh2 : eh3;
    size_t sb = (size_t)s * 128, db = (size_t)d * 128;
    atomicAdd(&acc[db + lane],      exLo * xw[sb + lane]);
    atomicAdd(&acc[db + 64 + lane], exHi * xw[sb + 64 + lane]);
}

// ---------------- finalize layer 1: h = elu(acc/den + b1), in place ----------------
__global__ __launch_bounds__(256) void k_finalize1(
    float* __restrict__ acc, const float* __restrict__ den, const float* __restrict__ b, int N)
{
    int idx = blockIdx.x * 256 + threadIdx.x;
    if (idx >= N * 128) return;
    int n = idx >> 7, j = idx & 127, h = j >> 5;
    float v = acc[idx] / (den[n * 4 + h] + 1e-16f) + b[j];
    acc[idx] = v > 0.f ? v : expm1f(v);
}

// ---------------- edge max, layer 2 (1 head) ----------------
__global__ __launch_bounds__(256) void k_edge_max2(
    const int* __restrict__ ei, const float* __restrict__ as, const float* __restrict__ ad,
    unsigned* __restrict__ m, int E, int ET)
{
    int t = blockIdx.x * 256 + threadIdx.x;
    if (t >= ET) return;
    int s, d;
    if (t < E) { s = ei[t]; d = ei[E + t]; } else { s = d = t - E; }
    atomicMax(&m[d], fenc(lrelu(as[s] + ad[d])));
}

// ---------------- edge scatter, layer 2: 32 lanes per edge ----------------
__global__ __launch_bounds__(256) void k_scatter2(
    const int* __restrict__ ei, const float* __restrict__ as, const float* __restrict__ ad,
    const unsigned* __restrict__ m, const float* __restrict__ xw,
    float* __restrict__ den, float* __restrict__ acc, int E, int ET)
{
    int t = blockIdx.x * 8 + (threadIdx.x >> 5);
    int c = threadIdx.x & 31;
    if (t >= ET) return;
    int s, d;
    if (t < E) { s = ei[t]; d = ei[E + t]; } else { s = d = t - E; }
    float ex = __expf(lrelu(as[s] + ad[d]) - fdec(m[d]));
    if (c == 0) atomicAdd(&den[d], ex);
    atomicAdd(&acc[(size_t)d * 32 + c], ex * xw[(size_t)s * 32 + c]);
}

// ---------------- final: z = (acc/den + b2), row-normalize, write out ----------------
__global__ __launch_bounds__(256) void k_final(
    const float* __restrict__ acc, const float* __restrict__ den,
    const float* __restrict__ b, float* __restrict__ out, int N)
{
    int n = blockIdx.x * 8 + (threadIdx.x >> 5);
    int c = threadIdx.x & 31;
    if (n >= N) return;
    float v = acc[(size_t)n * 32 + c] / (den[n] + 1e-16f) + b[c];
    float ss = v * v;
    ss += __shfl_xor(ss, 1, 32);
    ss += __shfl_xor(ss, 2, 32);
    ss += __shfl_xor(ss, 4, 32);
    ss += __shfl_xor(ss, 8, 32);
    ss += __shfl_xor(ss, 16, 32);
    out[(size_t)n * 32 + c] = v / sqrtf(ss);
}

// ---------------- host launch ----------------
extern "C" void kernel_launch(void* const* d_in, const int* in_sizes, int n_in,
                              void* d_out, int out_size, void* d_ws, size_t ws_size,
                              hipStream_t stream)
{
    const float* x   = (const float*)d_in[0];
    const int*   ei  = (const int*)d_in[1];
    const float* W1  = (const float*)d_in[2];
    const float* as1 = (const float*)d_in[3];
    const float* ad1 = (const float*)d_in[4];
    const float* b1  = (const float*)d_in[5];
    const float* W2  = (const float*)d_in[6];
    const float* as2 = (const float*)d_in[7];
    const float* ad2 = (const float*)d_in[8];
    const float* b2  = (const float*)d_in[9];
    float* out = (float*)d_out;

    const int N  = in_sizes[0] / 128;
    const int E  = in_sizes[1] / 2;
    const int ET = E + N;

    char* ws = (char*)d_ws;
    float*    xwA   = (float*)(ws);                               // N*128 f32
    float*    accB  = (float*)(ws + (size_t)N * 128 * 4);         // N*128 f32
    float*    asrcB = (float*)(ws + (size_t)N * 128 * 4 * 2);     // N*4 f32
    float*    adstB = asrcB + (size_t)N * 4;                      // N*4 f32
    unsigned* mB    = (unsigned*)(adstB + (size_t)N * 4);         // N*4 u32
    float*    denB  = (float*)(mB + (size_t)N * 4);               // N*4 f32

    // ---- layer 1 ----
    hipMemsetAsync(mB,   0, (size_t)N * 4 * 4, stream);
    hipMemsetAsync(denB, 0, (size_t)N * 4 * 4, stream);
    hipMemsetAsync(accB, 0, (size_t)N * 128 * 4, stream);
    k_gemm1<<<(N + 31) / 32, 256, 0, stream>>>(x, W1, as1, ad1, xwA, asrcB, adstB, N);
    k_edge_max1<<<(ET + 255) / 256, 256, 0, stream>>>(
        ei, (const float4*)asrcB, (const float4*)adstB, mB, E, ET);
    k_scatter1<<<(ET + 3) / 4, 256, 0, stream>>>(
        ei, (const float4*)asrcB, (const float4*)adstB, mB, xwA, denB, accB, E, ET);
    k_finalize1<<<((size_t)N * 128 + 255) / 256, 256, 0, stream>>>(accB, denB, b1, N);

    // ---- layer 2 ----
    k_gemm2<<<(N + 63) / 64, 256, 0, stream>>>(accB, W2, as2, ad2, xwA, asrcB, adstB, N);
    hipMemsetAsync(mB,   0, (size_t)N * 4, stream);
    hipMemsetAsync(denB, 0, (size_t)N * 4, stream);
    hipMemsetAsync(accB, 0, (size_t)N * 32 * 4, stream);
    k_edge_max2<<<(ET + 255) / 256, 256, 0, stream>>>(ei, asrcB, adstB, mB, E, ET);
    k_scatter2<<<(ET + 7) / 8, 256, 0, stream>>>(ei, asrcB, adstB, mB, xwA, denB, accB, E, ET);
    k_final<<<(N + 7) / 8, 256, 0, stream>>>(accB, denB, b2, out, N);
}

// Round 2
// 515.298 us; speedup vs baseline: 3.2915x; 3.2915x over previous
//
#include <hip/hip_runtime.h>
#include <math.h>

__device__ __forceinline__ float lrelu(float x) { return x > 0.f ? x : 0.2f * x; }

// ---------------- layer-1 GEMM: xw = x @ W1  [N,128]x[128,128], fused alpha dots ----------------
__global__ __launch_bounds__(256) void k_gemm1(
    const float* __restrict__ x, const float* __restrict__ W,
    const float* __restrict__ att_s, const float* __restrict__ att_d,
    float* __restrict__ xw, float* __restrict__ asrc, float* __restrict__ adst, int N)
{
    __shared__ float ws[64 * 128];   // half of W (32KB)
    __shared__ float xs[128 * 32];   // x tile transposed [k][node] (16KB)
    const int tid = threadIdx.x;
    const int cg = tid & 31;
    const int ng = tid >> 5;
    const int nb = blockIdx.x * 32;

    #pragma unroll
    for (int i = 0; i < 16; i++) {
        int q = i * 256 + tid;        // q = nl*128 + k
        int nl = q >> 7, k = q & 127;
        int n = nb + nl;
        xs[k * 32 + nl] = (n < N) ? x[(size_t)n * 128 + k] : 0.f;
    }

    float acc[4][4];
    #pragma unroll
    for (int i = 0; i < 4; i++)
        #pragma unroll
        for (int j = 0; j < 4; j++) acc[i][j] = 0.f;

    for (int half = 0; half < 2; half++) {
        __syncthreads();
        #pragma unroll
        for (int i = 0; i < 32; i++) {
            int q = i * 256 + tid;
            ws[q] = W[half * 8192 + q];
        }
        __syncthreads();
        #pragma unroll 8
        for (int kk = 0; kk < 64; kk++) {
            int k = half * 64 + kk;
            float4 wv = ((const float4*)ws)[kk * 32 + cg];
            float4 xv = ((const float4*)xs)[k * 8 + ng];
            float xa[4] = {xv.x, xv.y, xv.z, xv.w};
            float wa[4] = {wv.x, wv.y, wv.z, wv.w};
            #pragma unroll
            for (int i = 0; i < 4; i++)
                #pragma unroll
                for (int j = 0; j < 4; j++)
                    acc[i][j] += xa[i] * wa[j];
        }
    }

    const int c0 = cg * 4;
    #pragma unroll
    for (int i = 0; i < 4; i++) {
        int n = nb + ng * 4 + i;
        float t1 = acc[i][0] * att_s[c0 + 0] + acc[i][1] * att_s[c0 + 1] +
                   acc[i][2] * att_s[c0 + 2] + acc[i][3] * att_s[c0 + 3];
        float t2 = acc[i][0] * att_d[c0 + 0] + acc[i][1] * att_d[c0 + 1] +
                   acc[i][2] * att_d[c0 + 2] + acc[i][3] * att_d[c0 + 3];
        t1 += __shfl_xor(t1, 1, 8); t1 += __shfl_xor(t1, 2, 8); t1 += __shfl_xor(t1, 4, 8);
        t2 += __shfl_xor(t2, 1, 8); t2 += __shfl_xor(t2, 2, 8); t2 += __shfl_xor(t2, 4, 8);
        if (n < N) {
            ((float4*)xw)[(size_t)n * 32 + cg] =
                make_float4(acc[i][0], acc[i][1], acc[i][2], acc[i][3]);
            if ((cg & 7) == 0) {
                asrc[n * 4 + (cg >> 3)] = t1;
                adst[n * 4 + (cg >> 3)] = t2;
            }
        }
    }
}

// ---------------- layer-2 GEMM: xw2 = h @ W2 [N,128]x[128,32], fused alpha dots ----------------
__global__ __launch_bounds__(256) void k_gemm2(
    const float* __restrict__ h, const float* __restrict__ W,
    const float* __restrict__ att_s, const float* __restrict__ att_d,
    float* __restrict__ xw, float* __restrict__ asrc, float* __restrict__ adst, int N)
{
    __shared__ float ws[128 * 32];  // 16KB
    __shared__ float xs[128 * 64];  // 32KB, transposed [k][node]
    const int tid = threadIdx.x;
    const int cg = tid & 7;
    const int ng = tid >> 3;
    const int nb = blockIdx.x * 64;

    #pragma unroll
    for (int i = 0; i < 16; i++) { int q = i * 256 + tid; ws[q] = W[q]; }
    #pragma unroll
    for (int i = 0; i < 32; i++) {
        int q = i * 256 + tid;
        int nl = q >> 7, k = q & 127;
        int n = nb + nl;
        xs[k * 64 + nl] = (n < N) ? h[(size_t)n * 128 + k] : 0.f;
    }
    __syncthreads();

    float acc[2][4];
    #pragma unroll
    for (int i = 0; i < 2; i++)
        #pragma unroll
        for (int j = 0; j < 4; j++) acc[i][j] = 0.f;

    #pragma unroll 8
    for (int k = 0; k < 128; k++) {
        float4 wv = ((const float4*)ws)[k * 8 + cg];
        float2 xv = ((const float2*)xs)[k * 32 + ng];
        float wa[4] = {wv.x, wv.y, wv.z, wv.w};
        #pragma unroll
        for (int j = 0; j < 4; j++) {
            acc[0][j] += xv.x * wa[j];
            acc[1][j] += xv.y * wa[j];
        }
    }

    const int c0 = cg * 4;
    #pragma unroll
    for (int i = 0; i < 2; i++) {
        int n = nb + ng * 2 + i;
        float t1 = acc[i][0] * att_s[c0 + 0] + acc[i][1] * att_s[c0 + 1] +
                   acc[i][2] * att_s[c0 + 2] + acc[i][3] * att_s[c0 + 3];
        float t2 = acc[i][0] * att_d[c0 + 0] + acc[i][1] * att_d[c0 + 1] +
                   acc[i][2] * att_d[c0 + 2] + acc[i][3] * att_d[c0 + 3];
        t1 += __shfl_xor(t1, 1, 8); t1 += __shfl_xor(t1, 2, 8); t1 += __shfl_xor(t1, 4, 8);
        t2 += __shfl_xor(t2, 1, 8); t2 += __shfl_xor(t2, 2, 8); t2 += __shfl_xor(t2, 4, 8);
        if (n < N) {
            ((float4*)xw)[(size_t)n * 8 + cg] =
                make_float4(acc[i][0], acc[i][1], acc[i][2], acc[i][3]);
            if (cg == 0) { asrc[n] = t1; adst[n] = t2; }
        }
    }
}

// ---------------- CSR build ----------------
__global__ __launch_bounds__(256) void k_hist(
    const int* __restrict__ ei, unsigned* __restrict__ cnt, int E, int ET)
{
    for (int t = blockIdx.x * 256 + threadIdx.x; t < ET; t += gridDim.x * 256) {
        int d = (t < E) ? ei[E + t] : (t - E);
        atomicAdd(&cnt[d], 1u);
    }
}

__global__ __launch_bounds__(1024) void k_scan(
    const unsigned* __restrict__ cnt, unsigned* __restrict__ rowptr, int N)
{
    __shared__ unsigned part[1024];
    const int t = threadIdx.x;
    const int chunk = (N + 1023) >> 10;
    const int lo = t * chunk;
    const int hi = min(lo + chunk, N);
    unsigned s = 0;
    for (int i = lo; i < hi; i++) s += cnt[i];
    part[t] = s;
    __syncthreads();
    for (int off = 1; off < 1024; off <<= 1) {
        unsigned u = (t >= off) ? part[t - off] : 0u;
        __syncthreads();
        part[t] += u;
        __syncthreads();
    }
    unsigned run = part[t] - s;   // exclusive base for this chunk
    for (int i = lo; i < hi; i++) { rowptr[i] = run; run += cnt[i]; }
    if (t == 1023) rowptr[N] = part[1023];
}

__global__ __launch_bounds__(256) void k_fill(
    const int* __restrict__ ei, const unsigned* __restrict__ rowptr,
    unsigned* __restrict__ cursor, int* __restrict__ csr, int E, int ET)
{
    for (int t = blockIdx.x * 256 + threadIdx.x; t < ET; t += gridDim.x * 256) {
        int s, d;
        if (t < E) { s = ei[t]; d = ei[E + t]; } else { s = d = t - E; }
        unsigned pos = atomicAdd(&cursor[d], 1u);
        csr[rowptr[d] + pos] = s;
    }
}

// ---------------- layer-1 gather: wave per dst node, fused softmax+agg+finalize ----------------
__global__ __launch_bounds__(256) void k_gather1(
    const int* __restrict__ csr, const unsigned* __restrict__ rowptr,
    const float* __restrict__ as, const float* __restrict__ ad,
    const float* __restrict__ xw, const float* __restrict__ b,
    float* __restrict__ h, int N)
{
    const int n = blockIdx.x * 4 + (threadIdx.x >> 6);
    const int lane = threadIdx.x & 63;
    if (n >= N) return;
    const int h0 = lane >> 5;      // head of channel `lane`   (0 or 1)
    const int h1 = 2 + h0;         // head of channel 64+lane  (2 or 3)
    const unsigned row = rowptr[n];
    const int deg = (int)(rowptr[n + 1] - row);
    const float ad0 = ad[n * 4 + h0];
    const float ad1 = ad[n * 4 + h1];

    // phase 1: per-head max, edge-parallel within each 32-lane half
    float m0 = -1e30f, m1 = -1e30f;
    for (int i = (lane & 31); i < deg; i += 32) {
        int s = csr[row + i];
        m0 = fmaxf(m0, lrelu(as[s * 4 + h0] + ad0));
        m1 = fmaxf(m1, lrelu(as[s * 4 + h1] + ad1));
    }
    #pragma unroll
    for (int off = 1; off < 32; off <<= 1) {
        m0 = fmaxf(m0, __shfl_xor(m0, off, 32));
        m1 = fmaxf(m1, __shfl_xor(m1, off, 32));
    }

    // phase 2: exp + weighted accumulate (all lanes walk all edges together)
    float den0 = 0.f, den1 = 0.f, a0 = 0.f, a1 = 0.f;
    #pragma unroll 4
    for (int j = 0; j < deg; j++) {
        int s = csr[row + j];
        float e0 = __expf(lrelu(as[s * 4 + h0] + ad0) - m0);
        float e1 = __expf(lrelu(as[s * 4 + h1] + ad1) - m1);
        den0 += e0; den1 += e1;
        size_t sb = (size_t)s * 128;
        a0 += e0 * xw[sb + lane];
        a1 += e1 * xw[sb + 64 + lane];
    }

    float v0 = a0 / (den0 + 1e-16f) + b[lane];
    float v1 = a1 / (den1 + 1e-16f) + b[64 + lane];
    h[(size_t)n * 128 + lane]      = v0 > 0.f ? v0 : expm1f(v0);
    h[(size_t)n * 128 + 64 + lane] = v1 > 0.f ? v1 : expm1f(v1);
}

// ---------------- layer-2 gather: 32 lanes per node, fused finalize + L2-normalize ----------------
__global__ __launch_bounds__(256) void k_gather2(
    const int* __restrict__ csr, const unsigned* __restrict__ rowptr,
    const float* __restrict__ as, const float* __restrict__ ad,
    const float* __restrict__ xw, const float* __restrict__ b,
    float* __restrict__ out, int N)
{
    const int n = blockIdx.x * 8 + (threadIdx.x >> 5);
    const int c = threadIdx.x & 31;
    if (n >= N) return;
    const unsigned row = rowptr[n];
    const int deg = (int)(rowptr[n + 1] - row);
    const float adv = ad[n];

    float m = -1e30f;
    for (int i = c; i < deg; i += 32) {
        m = fmaxf(m, lrelu(as[csr[row + i]] + adv));
    }
    #pragma unroll
    for (int off = 1; off < 32; off <<= 1) m = fmaxf(m, __shfl_xor(m, off, 32));

    float den = 0.f, acc = 0.f;
    #pragma unroll 4
    for (int j = 0; j < deg; j++) {
        int s = csr[row + j];
        float e = __expf(lrelu(as[s] + adv) - m);
        den += e;
        acc += e * xw[(size_t)s * 32 + c];
    }

    float v = acc / (den + 1e-16f) + b[c];
    float ss = v * v;
    #pragma unroll
    for (int off = 1; off < 32; off <<= 1) ss += __shfl_xor(ss, off, 32);
    out[(size_t)n * 32 + c] = v / sqrtf(ss);
}

// ---------------- host launch ----------------
extern "C" void kernel_launch(void* const* d_in, const int* in_sizes, int n_in,
                              void* d_out, int out_size, void* d_ws, size_t ws_size,
                              hipStream_t stream)
{
    const float* x   = (const float*)d_in[0];
    const int*   ei  = (const int*)d_in[1];
    const float* W1  = (const float*)d_in[2];
    const float* as1 = (const float*)d_in[3];
    const float* ad1 = (const float*)d_in[4];
    const float* b1  = (const float*)d_in[5];
    const float* W2  = (const float*)d_in[6];
    const float* as2 = (const float*)d_in[7];
    const float* ad2 = (const float*)d_in[8];
    const float* b2  = (const float*)d_in[9];
    float* out = (float*)d_out;

    const int N  = in_sizes[0] / 128;
    const int E  = in_sizes[1] / 2;
    const int ET = E + N;

    float*    xwA    = (float*)d_ws;                 // N*128 (layer1 xw; reused as layer2 xw N*32)
    float*    hB     = xwA + (size_t)N * 128;        // N*128
    float*    asrcB  = hB + (size_t)N * 128;         // N*4
    float*    adstB  = asrcB + (size_t)N * 4;        // N*4
    unsigned* rowptr = (unsigned*)(adstB + (size_t)N * 4);  // N+1
    unsigned* cnt    = rowptr + (N + 1);             // N
    int*      csr    = (int*)(cnt + N);              // ET

    // ---- CSR build (shared by both layers) ----
    hipMemsetAsync(cnt, 0, (size_t)N * 4, stream);
    k_hist<<<2048, 256, 0, stream>>>(ei, cnt, E, ET);
    k_scan<<<1, 1024, 0, stream>>>(cnt, rowptr, N);
    hipMemsetAsync(cnt, 0, (size_t)N * 4, stream);
    k_fill<<<2048, 256, 0, stream>>>(ei, rowptr, cnt, csr, E, ET);

    // ---- layer 1 ----
    k_gemm1<<<(N + 31) / 32, 256, 0, stream>>>(x, W1, as1, ad1, xwA, asrcB, adstB, N);
    k_gather1<<<(N + 3) / 4, 256, 0, stream>>>(csr, rowptr, asrcB, adstB, xwA, b1, hB, N);

    // ---- layer 2 ----
    k_gemm2<<<(N + 63) / 64, 256, 0, stream>>>(hB, W2, as2, ad2, xwA, asrcB, adstB, N);
    k_gather2<<<(N + 7) / 8, 256, 0, stream>>>(csr, rowptr, asrcB, adstB, xwA, b2, out, N);
}